// Round 1
// baseline (320.300 us; speedup 1.0000x reference)
//
#include <hip/hip_runtime.h>
#include <stdint.h>

typedef uint32_t u32;
typedef uint64_t u64;

#define BN 16
#define CLS 80
#define ROWF 85
#define KSEL 512
#define CONF_T 0.001f
#define NMS_T 0.5f

__device__ __forceinline__ u32 flip_desc(float x) {
    u32 u = __float_as_uint(x);
    u32 m = (u & 0x80000000u) ? ~u : (u | 0x80000000u); // monotonic ascending
    return ~m;                                          // descending key
}

// ---------------- K1: per-row conf key ----------------
__global__ void k1_keys(const float* __restrict__ pred, u32* __restrict__ keys, int totalRows) {
    __shared__ float buf[256 * ROWF]; // 87,040 B
    long long base = (long long)blockIdx.x * 256 * ROWF;
    int nrow = min(256, totalRows - blockIdx.x * 256);
    if (nrow <= 0) return;
    int nflt = nrow * ROWF;
    for (int k = threadIdx.x; k < nflt; k += 256) buf[k] = pred[base + k];
    __syncthreads();
    int r = threadIdx.x;
    if (r < nrow) {
        const float* p = &buf[r * ROWF];
        float obj = p[4];
        float mx = p[5];
        #pragma unroll
        for (int c = 1; c < CLS; c++) { float v = p[5 + c]; if (v > mx) mx = v; }
        float conf = obj * mx;
        float w = p[2], h = p[3];
        bool ok = (conf > CONF_T) && (w > 2.0f) && (w < 10000.0f) && (h > 2.0f) && (h < 10000.0f);
        bool fin = true;
        #pragma unroll
        for (int c = 0; c < ROWF; c++) {
            u32 bb = __float_as_uint(p[c]);
            if ((bb & 0x7f800000u) == 0x7f800000u) fin = false;
        }
        ok = ok && fin;
        float cm = ok ? conf : -1.0f;
        keys[(long long)blockIdx.x * 256 + r] = flip_desc(cm);
    }
}

// ---------------- K2: exact top-K per image (radix select + bitonic) ----------------
__global__ void k2_select(const u32* __restrict__ keys, u32* __restrict__ selidx,
                          u32* __restrict__ tiebuf, int N) {
    int b = blockIdx.x;
    const u32* kk = keys + (long long)b * N;
    u32* tb = tiebuf + (long long)b * N;
    __shared__ u32 hist[256];
    __shared__ u32 sh_prefix, sh_rem, sh_nless, sh_ntie, sh_cnt2, sh_tieT, sh_tierem;
    __shared__ u64 skey[KSEL];
    int tid = threadIdx.x; // 256 threads
    if (tid == 0) { sh_prefix = 0; sh_rem = KSEL; }
    // 4-pass radix select on 32-bit key (find K-th smallest value T)
    for (int byte = 3; byte >= 0; byte--) {
        __syncthreads();
        hist[tid] = 0;
        __syncthreads();
        u32 pfx = sh_prefix;
        int shiftHi = (byte + 1) * 8;
        for (int i = tid; i < N; i += 256) {
            u32 e = kk[i];
            if (byte == 3 || (e >> shiftHi) == pfx) atomicAdd(&hist[(e >> (byte * 8)) & 255], 1);
        }
        __syncthreads();
        if (tid == 0) {
            u32 rem = sh_rem, cum = 0; int c = 0;
            for (; c < 256; c++) { if (cum + hist[c] >= rem) break; cum += hist[c]; }
            sh_rem = rem - cum;
            sh_prefix = (pfx << 8) | (u32)c;
        }
    }
    __syncthreads();
    u32 T = sh_prefix;
    if (tid == 0) { sh_nless = 0; sh_ntie = 0; }
    __syncthreads();
    for (int i = tid; i < N; i += 256) {
        u32 e = kk[i];
        if (e < T) { u32 p = atomicAdd(&sh_nless, 1); skey[p] = ((u64)e << 32) | (u32)i; }
        else if (e == T) { u32 p = atomicAdd(&sh_ntie, 1); tb[p] = (u32)i; }
    }
    __syncthreads();
    u32 nless = sh_nless, ntie = sh_ntie;
    u32 t = KSEL - nless;
    if (t == ntie) {
        for (u32 j = tid; j < t; j += 256) skey[nless + j] = ((u64)T << 32) | tb[j];
    } else {
        // select t smallest indices among ties (2-pass radix on 16-bit idx)
        if (tid == 0) { sh_tieT = 0; sh_tierem = t; }
        for (int byte = 1; byte >= 0; byte--) {
            __syncthreads();
            hist[tid] = 0;
            __syncthreads();
            u32 pfx = sh_tieT;
            int shiftHi = (byte + 1) * 8;
            for (u32 i = tid; i < ntie; i += 256) {
                u32 e = tb[i];
                if (byte == 1 || (e >> shiftHi) == pfx) atomicAdd(&hist[(e >> (byte * 8)) & 255], 1);
            }
            __syncthreads();
            if (tid == 0) {
                u32 rem = sh_tierem, cum = 0; int c = 0;
                for (; c < 256; c++) { if (cum + hist[c] >= rem) break; cum += hist[c]; }
                sh_tierem = rem - cum;
                sh_tieT = (pfx << 8) | (u32)c;
            }
        }
        __syncthreads();
        u32 Ti = sh_tieT;
        if (tid == 0) sh_cnt2 = 0;
        __syncthreads();
        for (u32 i = tid; i < ntie; i += 256) {
            u32 e = tb[i];
            if (e <= Ti) { u32 p = atomicAdd(&sh_cnt2, 1); skey[nless + p] = ((u64)T << 32) | e; }
        }
    }
    __syncthreads();
    // bitonic sort 512 u64 ascending => conf desc, idx asc on ties (== lax.top_k order)
    for (int k = 2; k <= KSEL; k <<= 1) {
        for (int j = k >> 1; j > 0; j >>= 1) {
            for (int i = tid; i < KSEL; i += 256) {
                int l = i ^ j;
                if (l > i) {
                    bool dir = ((i & k) == 0);
                    u64 a = skey[i], c = skey[l];
                    if ((a > c) == dir) { skey[i] = c; skey[l] = a; }
                }
            }
            __syncthreads();
        }
    }
    for (int i = tid; i < KSEL; i += 256) selidx[b * KSEL + i] = (u32)(skey[i] & 0xffffffffu);
}

// ---------------- K3: gather selected rows, compute obox/conf/cc/cp/ok ----------------
__global__ void k3_gather(const float* __restrict__ pred, const u32* __restrict__ selidx,
                          float* __restrict__ sel, int N) {
    int g = blockIdx.x * blockDim.x + threadIdx.x;
    if (g >= BN * KSEL) return;
    int b = g / KSEL;
    int idx = (int)selidx[g];
    const float* row = pred + ((long long)b * N + idx) * ROWF;
    float obj = row[4];
    float mx = row[5]; int am = 0;
    for (int c = 1; c < CLS; c++) { float v = row[5 + c]; if (v > mx) { mx = v; am = c; } }
    float conf = obj * mx;
    float cx = row[0], cy = row[1], w = row[2], h = row[3];
    bool ok = (conf > CONF_T) && (w > 2.0f) && (w < 10000.0f) && (h > 2.0f) && (h < 10000.0f);
    bool fin = true;
    for (int c = 0; c < ROWF; c++) {
        u32 bb = __float_as_uint(row[c]);
        if ((bb & 0x7f800000u) == 0x7f800000u) fin = false;
    }
    ok = ok && fin;
    float off = (float)am * 10000.0f;
    float x1 = cx - w * 0.5f, y1 = cy - h * 0.5f;
    float x2 = cx + w * 0.5f, y2 = cy + h * 0.5f;
    float* s = sel + (long long)g * 8;
    s[0] = x1 + off; s[1] = y1; s[2] = x2 + off; s[3] = y2;
    s[4] = conf; s[5] = mx; s[6] = (float)am; s[7] = ok ? 1.0f : 0.0f;
}

// ---------------- K4: 512x512 iou>thres bitmatrix ----------------
__global__ void k4_iou(const float* __restrict__ sel, u64* __restrict__ mat) {
    int g = blockIdx.x * blockDim.x + threadIdx.x; // BN*KSEL*8
    if (g >= BN * KSEL * 8) return;
    int w = g & 7;
    int i = (g >> 3) & (KSEL - 1);
    int b = g >> 12;
    const float* S = sel + (long long)b * KSEL * 8;
    const float* bi = S + i * 8;
    float x1 = bi[0], y1 = bi[1], x2 = bi[2], y2 = bi[3];
    float a1 = __fmul_rn(__fsub_rn(x2, x1), __fsub_rn(y2, y1));
    u64 bits = 0;
    int j0 = w * 64;
    for (int jj = 0; jj < 64; jj++) {
        const float* bj = S + (j0 + jj) * 8;
        float ix = fmaxf(__fsub_rn(fminf(x2, bj[2]), fmaxf(x1, bj[0])), 0.0f);
        float iy = fmaxf(__fsub_rn(fminf(y2, bj[3]), fmaxf(y1, bj[1])), 0.0f);
        float inter = __fmul_rn(ix, iy);
        float a2 = __fmul_rn(__fsub_rn(bj[2], bj[0]), __fsub_rn(bj[3], bj[1]));
        float denom = __fadd_rn(__fsub_rn(__fadd_rn(a1, a2), inter), 1e-9f);
        float iou = __fdiv_rn(inter, denom);
        if (iou > NMS_T) bits |= (1ull << jj);
    }
    mat[(long long)b * KSEL * 8 + i * 8 + w] = bits;
}

// ---------------- K5: serial merge-NMS scan + compacted output ----------------
__global__ __launch_bounds__(64) void k5_nms(const float* __restrict__ sel,
                                             const u64* __restrict__ mat,
                                             float* __restrict__ out) {
    int b = blockIdx.x;
    int lane = threadIdx.x;
    __shared__ float S[KSEL * 8];  // 16 KB
    __shared__ u64 M[KSEL * 8];    // 32 KB
    __shared__ float MG[KSEL * 4]; // 8 KB merged boxes
    const float* gs = sel + (long long)b * KSEL * 8;
    const u64* gm = mat + (long long)b * KSEL * 8;
    for (int i = lane; i < KSEL * 8; i += 64) { S[i] = gs[i]; M[i] = gm[i]; }
    __syncthreads();
    for (int i = lane; i < KSEL; i += 64) {
        MG[i * 4 + 0] = S[i * 8 + 0]; MG[i * 4 + 1] = S[i * 8 + 1];
        MG[i * 4 + 2] = S[i * 8 + 2]; MG[i * 4 + 3] = S[i * 8 + 3];
    }
    u64 aliveW[8], keepW[8];
    #pragma unroll
    for (int w = 0; w < 8; w++) {
        bool okb = S[(w * 64 + lane) * 8 + 7] > 0.5f;
        aliveW[w] = __ballot(okb);
        keepW[w] = 0;
    }
    __syncthreads();
    // serial scan: everything below is wave-uniform
    for (int i = 0; i < KSEL; i++) {
        int wi = i >> 6, bi = i & 63;
        if (!((aliveW[wi] >> bi) & 1ull)) continue;
        keepW[wi] |= (1ull << bi);
        u64 selW[8]; int pc = 0;
        #pragma unroll
        for (int w = 0; w < 8; w++) { selW[w] = M[i * 8 + w] & aliveW[w]; pc += __popcll(selW[w]); }
        if (pc > 1) {
            float s0 = 0.f, s1 = 0.f, s2 = 0.f, s3 = 0.f, sw = 0.f;
            for (int w = 0; w < 8; w++) {
                u64 m_ = selW[w];
                while (m_) {
                    int j = w * 64 + __builtin_ctzll(m_);
                    m_ &= m_ - 1;
                    float c = S[j * 8 + 4];
                    s0 += c * S[j * 8 + 0]; s1 += c * S[j * 8 + 1];
                    s2 += c * S[j * 8 + 2]; s3 += c * S[j * 8 + 3];
                    sw += c;
                }
            }
            float d = sw + 1e-12f;
            if (lane == 0) {
                MG[i * 4 + 0] = s0 / d; MG[i * 4 + 1] = s1 / d;
                MG[i * 4 + 2] = s2 / d; MG[i * 4 + 3] = s3 / d;
            }
        }
        #pragma unroll
        for (int w = 0; w < 8; w++) aliveW[w] &= ~selW[w];
    }
    __syncthreads();
    int nk = 0;
    #pragma unroll
    for (int w = 0; w < 8; w++) nk += __popcll(keepW[w]);
    float* ob = out + (long long)b * KSEL * 7;
    for (int i = lane; i < KSEL; i += 64) {
        int wi = i >> 6, bi = i & 63;
        if ((keepW[wi] >> bi) & 1ull) {
            int rank = 0;
            for (int w = 0; w < wi; w++) rank += __popcll(keepW[w]);
            rank += __popcll(keepW[wi] & ((1ull << bi) - 1ull));
            float off = S[i * 8 + 6] * 10000.0f;
            float* o = ob + rank * 7;
            o[0] = MG[i * 4 + 0] - off; o[1] = MG[i * 4 + 1];
            o[2] = MG[i * 4 + 2] - off; o[3] = MG[i * 4 + 3];
            o[4] = S[i * 8 + 4]; o[5] = S[i * 8 + 5]; o[6] = S[i * 8 + 6];
        }
    }
    for (int p = nk + lane; p < KSEL; p += 64) {
        float* o = ob + p * 7;
        #pragma unroll
        for (int c = 0; c < 7; c++) o[c] = 0.0f;
    }
}

extern "C" void kernel_launch(void* const* d_in, const int* in_sizes, int n_in,
                              void* d_out, int out_size, void* d_ws, size_t ws_size,
                              hipStream_t stream) {
    const float* pred = (const float*)d_in[0];
    float* out = (float*)d_out;
    int total = in_sizes[0];
    int N = total / (BN * ROWF); // 22743
    int totalRows = BN * N;

    char* ws = (char*)d_ws;
    size_t o = 0;
    u32* keys = (u32*)(ws + o);   o += (size_t)totalRows * 4;
    u32* tiebuf = (u32*)(ws + o); o += (size_t)totalRows * 4;
    u32* selidx = (u32*)(ws + o); o += (size_t)BN * KSEL * 4;
    float* sel = (float*)(ws + o); o += (size_t)BN * KSEL * 8 * 4;
    u64* mat = (u64*)(ws + o);    o += (size_t)BN * KSEL * 8 * 8;
    (void)ws_size;

    k1_keys<<<(totalRows + 255) / 256, 256, 0, stream>>>(pred, keys, totalRows);
    k2_select<<<BN, 256, 0, stream>>>(keys, selidx, tiebuf, N);
    k3_gather<<<(BN * KSEL + 255) / 256, 256, 0, stream>>>(pred, selidx, sel, N);
    k4_iou<<<(BN * KSEL * 8 + 255) / 256, 256, 0, stream>>>(sel, mat);
    k5_nms<<<BN, 64, 0, stream>>>(sel, mat, out);
}

// Round 2
// 270.328 us; speedup vs baseline: 1.1849x; 1.1849x over previous
//
#include <hip/hip_runtime.h>
#include <stdint.h>

typedef uint32_t u32;
typedef uint64_t u64;

#define BN 16
#define CLS 80
#define ROWF 85
#define KSEL 512
#define CONF_T 0.001f
#define NMS_T 0.5f

__device__ __forceinline__ u32 flip_desc(float x) {
    u32 u = __float_as_uint(x);
    u32 m = (u & 0x80000000u) ? ~u : (u | 0x80000000u); // monotonic ascending
    return ~m;                                          // descending key
}

// ---------------- K1: per-row conf key (128 rows/block, float4-staged) ----------------
__global__ __launch_bounds__(128) void k1_keys(const float* __restrict__ pred,
                                               u32* __restrict__ keys, int totalRows) {
    __shared__ float buf[128 * ROWF]; // 43,520 B -> 3 blocks/CU
    int nrow = min(128, totalRows - blockIdx.x * 128);
    if (nrow <= 0) return;
    int nf4 = nrow * ROWF / 4;                 // nrow multiple of 4 except possibly last (112) -> still /4 exact
    const float4* p4 = (const float4*)pred;
    float4* b4 = (float4*)buf;
    long long base4 = (long long)blockIdx.x * (128 * ROWF / 4);
    for (int k = threadIdx.x; k < nf4; k += 128) b4[k] = p4[base4 + k];
    __syncthreads();
    int r = threadIdx.x;
    if (r < nrow) {
        const float* p = &buf[r * ROWF];
        float obj = p[4];
        float mx = p[5];
        #pragma unroll
        for (int c = 1; c < CLS; c++) { float v = p[5 + c]; if (v > mx) mx = v; }
        float conf = obj * mx;
        float w = p[2], h = p[3];
        bool ok = (conf > CONF_T) && (w > 2.0f) && (w < 10000.0f) && (h > 2.0f) && (h < 10000.0f);
        bool fin = true;
        #pragma unroll
        for (int c = 0; c < ROWF; c++) {
            u32 bb = __float_as_uint(p[c]);
            if ((bb & 0x7f800000u) == 0x7f800000u) fin = false;
        }
        ok = ok && fin;
        float cm = ok ? conf : -1.0f;
        keys[(long long)blockIdx.x * 128 + r] = flip_desc(cm);
    }
}

// ---------------- K2: exact top-K per image (radix select + bitonic) ----------------
__global__ void k2_select(const u32* __restrict__ keys, u32* __restrict__ selidx,
                          u32* __restrict__ tiebuf, int N) {
    int b = blockIdx.x;
    const u32* kk = keys + (long long)b * N;
    u32* tb = tiebuf + (long long)b * N;
    __shared__ u32 hist[256];
    __shared__ u32 sh_prefix, sh_rem, sh_nless, sh_ntie, sh_cnt2, sh_tieT, sh_tierem;
    __shared__ u64 skey[KSEL];
    int tid = threadIdx.x; // 256 threads
    if (tid == 0) { sh_prefix = 0; sh_rem = KSEL; }
    for (int byte = 3; byte >= 0; byte--) {
        __syncthreads();
        hist[tid] = 0;
        __syncthreads();
        u32 pfx = sh_prefix;
        int shiftHi = (byte + 1) * 8;
        for (int i = tid; i < N; i += 256) {
            u32 e = kk[i];
            if (byte == 3 || (e >> shiftHi) == pfx) atomicAdd(&hist[(e >> (byte * 8)) & 255], 1);
        }
        __syncthreads();
        if (tid == 0) {
            u32 rem = sh_rem, cum = 0; int c = 0;
            for (; c < 256; c++) { if (cum + hist[c] >= rem) break; cum += hist[c]; }
            sh_rem = rem - cum;
            sh_prefix = (pfx << 8) | (u32)c;
        }
    }
    __syncthreads();
    u32 T = sh_prefix;
    if (tid == 0) { sh_nless = 0; sh_ntie = 0; }
    __syncthreads();
    for (int i = tid; i < N; i += 256) {
        u32 e = kk[i];
        if (e < T) { u32 p = atomicAdd(&sh_nless, 1); skey[p] = ((u64)e << 32) | (u32)i; }
        else if (e == T) { u32 p = atomicAdd(&sh_ntie, 1); tb[p] = (u32)i; }
    }
    __syncthreads();
    u32 nless = sh_nless, ntie = sh_ntie;
    u32 t = KSEL - nless;
    if (t == ntie) {
        for (u32 j = tid; j < t; j += 256) skey[nless + j] = ((u64)T << 32) | tb[j];
    } else {
        if (tid == 0) { sh_tieT = 0; sh_tierem = t; }
        for (int byte = 1; byte >= 0; byte--) {
            __syncthreads();
            hist[tid] = 0;
            __syncthreads();
            u32 pfx = sh_tieT;
            int shiftHi = (byte + 1) * 8;
            for (u32 i = tid; i < ntie; i += 256) {
                u32 e = tb[i];
                if (byte == 1 || (e >> shiftHi) == pfx) atomicAdd(&hist[(e >> (byte * 8)) & 255], 1);
            }
            __syncthreads();
            if (tid == 0) {
                u32 rem = sh_tierem, cum = 0; int c = 0;
                for (; c < 256; c++) { if (cum + hist[c] >= rem) break; cum += hist[c]; }
                sh_tierem = rem - cum;
                sh_tieT = (pfx << 8) | (u32)c;
            }
        }
        __syncthreads();
        u32 Ti = sh_tieT;
        if (tid == 0) sh_cnt2 = 0;
        __syncthreads();
        for (u32 i = tid; i < ntie; i += 256) {
            u32 e = tb[i];
            if (e <= Ti) { u32 p = atomicAdd(&sh_cnt2, 1); skey[nless + p] = ((u64)T << 32) | e; }
        }
    }
    __syncthreads();
    for (int k = 2; k <= KSEL; k <<= 1) {
        for (int j = k >> 1; j > 0; j >>= 1) {
            for (int i = tid; i < KSEL; i += 256) {
                int l = i ^ j;
                if (l > i) {
                    bool dir = ((i & k) == 0);
                    u64 a = skey[i], c = skey[l];
                    if ((a > c) == dir) { skey[i] = c; skey[l] = a; }
                }
            }
            __syncthreads();
        }
    }
    for (int i = tid; i < KSEL; i += 256) selidx[b * KSEL + i] = (u32)(skey[i] & 0xffffffffu);
}

// ---------------- K3: gather selected rows ----------------
__global__ void k3_gather(const float* __restrict__ pred, const u32* __restrict__ selidx,
                          float* __restrict__ sel, int N) {
    int g = blockIdx.x * blockDim.x + threadIdx.x;
    if (g >= BN * KSEL) return;
    int b = g / KSEL;
    int idx = (int)selidx[g];
    const float* row = pred + ((long long)b * N + idx) * ROWF;
    float obj = row[4];
    float mx = row[5]; int am = 0;
    for (int c = 1; c < CLS; c++) { float v = row[5 + c]; if (v > mx) { mx = v; am = c; } }
    float conf = obj * mx;
    float cx = row[0], cy = row[1], w = row[2], h = row[3];
    bool ok = (conf > CONF_T) && (w > 2.0f) && (w < 10000.0f) && (h > 2.0f) && (h < 10000.0f);
    bool fin = true;
    for (int c = 0; c < ROWF; c++) {
        u32 bb = __float_as_uint(row[c]);
        if ((bb & 0x7f800000u) == 0x7f800000u) fin = false;
    }
    ok = ok && fin;
    float off = (float)am * 10000.0f;
    float x1 = cx - w * 0.5f, y1 = cy - h * 0.5f;
    float x2 = cx + w * 0.5f, y2 = cy + h * 0.5f;
    float* s = sel + (long long)g * 8;
    s[0] = x1 + off; s[1] = y1; s[2] = x2 + off; s[3] = y2;
    s[4] = conf; s[5] = mx; s[6] = (float)am; s[7] = ok ? 1.0f : 0.0f;
}

// ---------------- K4: 512x512 iou>thres bitmatrix, TRANSPOSED [b][w][i] ----------------
// grid: BN*16 blocks of 256. Within image: t in [0,4096), w = t>>9 (wave-uniform), i = t&511.
__global__ __launch_bounds__(256) void k4_iou(const float* __restrict__ sel, u64* __restrict__ matT) {
    int b = blockIdx.x >> 4;
    int t = ((blockIdx.x & 15) << 8) + threadIdx.x;
    int w = t >> 9;
    int i = t & (KSEL - 1);
    __shared__ float BX[KSEL * 4]; // 8KB
    const float* S = sel + (long long)b * KSEL * 8;
    const float4* S4 = (const float4*)S;
    float4* B4 = (float4*)BX;
    for (int j = threadIdx.x; j < KSEL; j += 256) B4[j] = S4[j * 2]; // first 4 floats of each box
    __syncthreads();
    float x1 = BX[i * 4 + 0], y1 = BX[i * 4 + 1], x2 = BX[i * 4 + 2], y2 = BX[i * 4 + 3];
    float a1 = __fmul_rn(__fsub_rn(x2, x1), __fsub_rn(y2, y1));
    u64 bits = 0;
    int j0 = w * 64;
    const float4* BB = (const float4*)BX;
    for (int jj = 0; jj < 64; jj++) {
        float4 bj = BB[j0 + jj]; // broadcast: whole wave shares w
        float ix = fmaxf(__fsub_rn(fminf(x2, bj.z), fmaxf(x1, bj.x)), 0.0f);
        float iy = fmaxf(__fsub_rn(fminf(y2, bj.w), fmaxf(y1, bj.y)), 0.0f);
        float inter = __fmul_rn(ix, iy);
        float a2 = __fmul_rn(__fsub_rn(bj.z, bj.x), __fsub_rn(bj.w, bj.y));
        float denom = __fadd_rn(__fsub_rn(__fadd_rn(a1, a2), inter), 1e-9f);
        float iou = __fdiv_rn(inter, denom);
        if (iou > NMS_T) bits |= (1ull << jj);
    }
    matT[((long long)b * 8 + w) * KSEL + i] = bits; // coalesced
}

// ---------------- K5: serial keep-scan (bitwise only) + parallel merge ----------------
__global__ __launch_bounds__(64) void k5_nms(const float* __restrict__ sel,
                                             const u64* __restrict__ matT,
                                             float* __restrict__ out) {
    int b = blockIdx.x;
    int lane = threadIdx.x;
    __shared__ float S[KSEL * 8];           // 16KB
    __shared__ u64 MT[8 * KSEL];            // 32KB, [w][i]
    __shared__ float MG[KSEL * 4];          // 8KB
    __shared__ unsigned short TGT[KSEL];    // 1KB
    const float4* gs = (const float4*)(sel + (long long)b * KSEL * 8);
    float4* s4 = (float4*)S;
    for (int i = lane; i < KSEL * 2; i += 64) s4[i] = gs[i];
    const ulonglong2* gm2 = (const ulonglong2*)(matT + (long long)b * 8 * KSEL);
    ulonglong2* m2 = (ulonglong2*)MT;
    for (int i = lane; i < 4 * KSEL; i += 64) m2[i] = gm2[i];
    __syncthreads();

    u64 aliveW[8], keepW[8], okW[8];
    #pragma unroll
    for (int w = 0; w < 8; w++) {
        bool okb = S[(w * 64 + lane) * 8 + 7] > 0.5f;
        okW[w] = __ballot(okb);
        aliveW[w] = okW[w];
        keepW[w] = 0;
    }

    // ---- phase 1: serial scan, pure bitmask algebra, 2-deep LDS prefetch ----
    u64 A[8], Bb[8];
    #pragma unroll
    for (int w = 0; w < 8; w++) { A[w] = MT[w * KSEL + 0]; Bb[w] = MT[w * KSEL + 1]; }
    #pragma unroll
    for (int wi = 0; wi < 8; wi++) {
        #pragma unroll 1
        for (int bi = 0; bi < 64; bi += 2) {
            int i = wi * 64 + bi;
            {
                u64 row[8];
                #pragma unroll
                for (int w = 0; w < 8; w++) row[w] = A[w];
                int ip = (i + 2 < KSEL) ? i + 2 : KSEL - 1;
                #pragma unroll
                for (int w = 0; w < 8; w++) A[w] = MT[w * KSEL + ip];
                if ((aliveW[wi] >> bi) & 1ull) {
                    keepW[wi] |= 1ull << bi;
                    #pragma unroll
                    for (int w = 0; w < 8; w++) aliveW[w] &= ~row[w];
                }
            }
            {
                u64 row[8];
                #pragma unroll
                for (int w = 0; w < 8; w++) row[w] = Bb[w];
                int ip = (i + 3 < KSEL) ? i + 3 : KSEL - 1;
                #pragma unroll
                for (int w = 0; w < 8; w++) Bb[w] = MT[w * KSEL + ip];
                if ((aliveW[wi] >> (bi + 1)) & 1ull) {
                    keepW[wi] |= 1ull << (bi + 1);
                    #pragma unroll
                    for (int w = 0; w < 8; w++) aliveW[w] &= ~row[w];
                }
            }
        }
    }

    // ---- phase 2a: per-column merge target = first kept bit of row j (M symmetric) ----
    #pragma unroll 1
    for (int r = 0; r < 8; r++) {
        int j = r * 64 + lane;
        int tgt = 0xffff;
        if ((okW[r] >> lane) & 1ull) {
            #pragma unroll
            for (int w = 7; w >= 0; w--) {
                u64 m = MT[w * KSEL + j] & keepW[w]; // lane-consecutive u64 -> conflict-free
                if (m) tgt = w * 64 + (int)__builtin_ctzll(m);
            }
        }
        TGT[j] = (unsigned short)tgt;
    }
    __syncthreads();

    // ---- phase 2b: per kept k, deterministic ascending-j weighted merge ----
    #pragma unroll 1
    for (int r = 0; r < 8; r++) {
        int k = r * 64 + lane;
        if ((keepW[r] >> lane) & 1ull) {
            float s0 = 0.f, s1 = 0.f, s2 = 0.f, s3 = 0.f, sw = 0.f;
            #pragma unroll 1
            for (int w = 0; w < 8; w++) {
                u64 m = MT[w * KSEL + k] & okW[w];
                while (m) {
                    int j = w * 64 + (int)__builtin_ctzll(m);
                    m &= m - 1;
                    if (TGT[j] == (unsigned short)k) {
                        float c = S[j * 8 + 4];
                        s0 += c * S[j * 8 + 0]; s1 += c * S[j * 8 + 1];
                        s2 += c * S[j * 8 + 2]; s3 += c * S[j * 8 + 3];
                        sw += c;
                    }
                }
            }
            float d = sw + 1e-12f;
            MG[k * 4 + 0] = s0 / d; MG[k * 4 + 1] = s1 / d;
            MG[k * 4 + 2] = s2 / d; MG[k * 4 + 3] = s3 / d;
        }
    }
    __syncthreads();

    // ---- output: compact kept rows in order, zero tail ----
    int nk = 0;
    #pragma unroll
    for (int w = 0; w < 8; w++) nk += __popcll(keepW[w]);
    float* ob = out + (long long)b * KSEL * 7;
    for (int i = lane; i < KSEL; i += 64) {
        int wi = i >> 6, bi = i & 63;
        if ((keepW[wi] >> bi) & 1ull) {
            int rank = 0;
            for (int w = 0; w < wi; w++) rank += __popcll(keepW[w]);
            rank += __popcll(keepW[wi] & ((1ull << bi) - 1ull));
            float off = S[i * 8 + 6] * 10000.0f;
            float* o = ob + rank * 7;
            o[0] = MG[i * 4 + 0] - off; o[1] = MG[i * 4 + 1];
            o[2] = MG[i * 4 + 2] - off; o[3] = MG[i * 4 + 3];
            o[4] = S[i * 8 + 4]; o[5] = S[i * 8 + 5]; o[6] = S[i * 8 + 6];
        }
    }
    for (int p = nk + lane; p < KSEL; p += 64) {
        float* o = ob + p * 7;
        #pragma unroll
        for (int c = 0; c < 7; c++) o[c] = 0.0f;
    }
}

extern "C" void kernel_launch(void* const* d_in, const int* in_sizes, int n_in,
                              void* d_out, int out_size, void* d_ws, size_t ws_size,
                              hipStream_t stream) {
    const float* pred = (const float*)d_in[0];
    float* out = (float*)d_out;
    int total = in_sizes[0];
    int N = total / (BN * ROWF); // 22743
    int totalRows = BN * N;

    char* ws = (char*)d_ws;
    size_t o = 0;
    u32* keys = (u32*)(ws + o);   o += (size_t)totalRows * 4;
    u32* tiebuf = (u32*)(ws + o); o += (size_t)totalRows * 4;
    u32* selidx = (u32*)(ws + o); o += (size_t)BN * KSEL * 4;
    float* sel = (float*)(ws + o); o += (size_t)BN * KSEL * 8 * 4;
    u64* matT = (u64*)(ws + o);   o += (size_t)BN * KSEL * 8 * 8;
    (void)ws_size;

    k1_keys<<<(totalRows + 127) / 128, 128, 0, stream>>>(pred, keys, totalRows);
    k2_select<<<BN, 256, 0, stream>>>(keys, selidx, tiebuf, N);
    k3_gather<<<(BN * KSEL + 255) / 256, 256, 0, stream>>>(pred, selidx, sel, N);
    k4_iou<<<BN * 16, 256, 0, stream>>>(sel, matT);
    k5_nms<<<BN, 64, 0, stream>>>(sel, matT, out);
}